// Round 3
// baseline (256.210 us; speedup 1.0000x reference)
//
#include <hip/hip_runtime.h>
#include <cfloat>
#include <cmath>

// Problem constants (fixed by the reference setup).
#define BB 64
#define NN 32768
#define CC 2
#define KK 10
#define S_SL 8                 // slices of N
#define SLICE (NN / S_SL)      // 4096 columns per slice
#define TPA 256                // threads for scan kernel
#define VLARGE 1.0e6
#define KEY_MAX 0xFFFFFFFFFFFFFFFFull

__device__ __forceinline__ float  sigf(float x)  { return 1.0f / (1.0f + expf(-x)); }
__device__ __forceinline__ double dsig(float x)  { return 1.0 / (1.0 + exp(-(double)x)); }
__device__ __forceinline__ double dsoftplus(double x) {
    return fmax(x, 0.0) + log1p(exp(-fabs(x)));
}
// cost >= 0 always (it's |sigmoid - target|^2, or +1e6), so the f32 bit
// pattern is monotone as u32 -> (cost, col) packs into one sortable u64.
__device__ __forceinline__ unsigned long long packkey(float v, int c) {
    return ((unsigned long long)__float_as_uint(v) << 32) | (unsigned int)c;
}
// merge two sorted top-2 lists (a1<=a2, b1<=b2) -> sorted top-2 in a1,a2
__device__ __forceinline__ void merge2(unsigned long long& a1, unsigned long long& a2,
                                       unsigned long long b1, unsigned long long b2) {
    unsigned long long lo = a1 < b1 ? a1 : b1;
    unsigned long long hi = a1 < b1 ? b1 : a1;
    unsigned long long mb = a2 < b2 ? a2 : b2;
    a2 = hi < mb ? hi : mb;
    a1 = lo;
}

// ---------------- Kernel A: wide f32 scan, per-row top-2 per slice ----------------
__global__ __launch_bounds__(TPA)
void scan_kernel(const float* __restrict__ p_start, const float* __restrict__ p_end,
                 const float* __restrict__ p_cls, const float* __restrict__ gt,
                 ulonglong2* __restrict__ cand) {
    const int sl  = blockIdx.x;
    const int b   = blockIdx.y;
    const int tid = threadIdx.x;
    const float*  ps  = p_start + (size_t)b * NN;
    const float*  pe  = p_end   + (size_t)b * NN;
    const float2* pc2 = (const float2*)(p_cls + (size_t)b * NN * CC);

    float rfs[KK], rfe[KK]; int rcl[KK], rabs[KK];
    #pragma unroll
    for (int k = 0; k < KK; k++) {
        float f0 = gt[((size_t)b * KK + k) * 3 + 0];
        float f1 = gt[((size_t)b * KK + k) * 3 + 1];
        float f2 = gt[((size_t)b * KK + k) * 3 + 2];
        bool pres = !(isnan(f0) || isnan(f1) || isnan(f2));
        if (isnan(f0)) f0 = 0.0f;
        if (isnan(f1)) f1 = 0.0f;
        if (isnan(f2)) f2 = 0.0f;
        int ci = (int)f2; ci = ci < 0 ? 0 : (ci > CC - 1 ? CC - 1 : ci);
        rfs[k] = f0; rfe[k] = f1; rcl[k] = ci; rabs[k] = pres ? 0 : 1;
    }

    float v1[KK], v2[KK]; int c1[KK], c2[KK];
    #pragma unroll
    for (int k = 0; k < KK; k++) { v1[k] = FLT_MAX; v2[k] = FLT_MAX; c1[k] = 0x7fffffff; c2[k] = 0x7fffffff; }

    const int base = sl * SLICE;
    for (int i = tid; i < SLICE; i += TPA) {
        const int n = base + i;
        const float s  = sigf(ps[n]);
        const float e  = sigf(pe[n]);
        const float2 cc = pc2[n];
        const float q0 = sigf(cc.x), q1 = sigf(cc.y);
        const float q  = q0 * q0 + q1 * q1 + 1.0f;
        #pragma unroll
        for (int k = 0; k < KK; k++) {
            const float d0 = s - rfs[k], d1 = e - rfe[k];
            const float sc = (rcl[k] == 0) ? q0 : q1;
            float cost = d0 * d0 + d1 * d1 + (q - 2.0f * sc);
            if (rabs[k]) cost = (float)VLARGE;
            // n ascends within a thread -> strict < keeps lowest column on ties
            if (cost < v2[k]) {
                if (cost < v1[k]) { v2[k] = v1[k]; c2[k] = c1[k]; v1[k] = cost; c1[k] = n; }
                else              { v2[k] = cost; c2[k] = n; }
            }
        }
    }

    // pack to sortable u64 keys, butterfly-merge across the wave
    unsigned long long k1[KK], k2[KK];
    #pragma unroll
    for (int k = 0; k < KK; k++) { k1[k] = packkey(v1[k], c1[k]); k2[k] = packkey(v2[k], c2[k]); }
    #pragma unroll
    for (int off = 1; off < 64; off <<= 1) {
        #pragma unroll
        for (int k = 0; k < KK; k++) {
            unsigned long long o1 = __shfl_xor(k1[k], off, 64);
            unsigned long long o2 = __shfl_xor(k2[k], off, 64);
            merge2(k1[k], k2[k], o1, o2);
        }
    }
    __shared__ unsigned long long s1[TPA / 64][KK], s2[TPA / 64][KK];
    const int wid = tid >> 6, lane = tid & 63;
    if (lane == 0) {
        #pragma unroll
        for (int k = 0; k < KK; k++) { s1[wid][k] = k1[k]; s2[wid][k] = k2[k]; }
    }
    __syncthreads();
    if (tid < KK) {
        unsigned long long a1 = s1[0][tid], a2 = s2[0][tid];
        #pragma unroll
        for (int w = 1; w < TPA / 64; w++) merge2(a1, a2, s1[w][tid], s2[w][tid]);
        ulonglong2 pk; pk.x = a1; pk.y = a2;
        cand[((size_t)b * S_SL + sl) * KK + tid] = pk;
    }
}

// f64 cost of (row targets, column)
__device__ __forceinline__ double eval64(const float* ps, const float* pe, const float* pc,
                                         double fs, double fe, int cls, int pres, int col) {
    if (!pres) return VLARGE;
    const double s  = dsig(ps[col]);
    const double e  = dsig(pe[col]);
    const double q0 = dsig(pc[2 * col]);
    const double q1 = dsig(pc[2 * col + 1]);
    const double d0 = s - fs, d1 = e - fe;
    const double sc = (cls == 0) ? q0 : q1;
    return d0 * d0 + d1 * d1 + (q0 * q0 + q1 * q1 - 2.0 * sc + 1.0);
}

// ---------------- Kernel B: single-wave per batch greedy matching + losses ----------------
__global__ __launch_bounds__(64)
void match_kernel(const float* __restrict__ p_start, const float* __restrict__ p_end,
                  const float* __restrict__ p_cls, const float* __restrict__ p_conf,
                  const float* __restrict__ gt, const ulonglong2* __restrict__ cand,
                  double* __restrict__ partials) {
    const int b = blockIdx.x, lane = threadIdx.x;
    const float* ps  = p_start + (size_t)b * NN;
    const float* pe  = p_end   + (size_t)b * NN;
    const float* pc  = p_cls   + (size_t)b * NN * CC;
    const float* pcf = p_conf  + (size_t)b * NN;

    __shared__ double g_fs[KK], g_fe[KK];
    __shared__ int    g_cls[KK], g_pres[KK];
    __shared__ double sd_cost[KK * 16];
    __shared__ int    sd_col[KK * 16];
    __shared__ int    s_prow[KK], s_pcol[KK], s_pvalid[KK], s_cons[KK];

    if (lane < KK) {
        float f0 = gt[((size_t)b * KK + lane) * 3 + 0];
        float f1 = gt[((size_t)b * KK + lane) * 3 + 1];
        float f2 = gt[((size_t)b * KK + lane) * 3 + 2];
        int pres = !(isnan(f0) || isnan(f1) || isnan(f2));
        if (isnan(f0)) f0 = 0.0f;
        if (isnan(f1)) f1 = 0.0f;
        if (isnan(f2)) f2 = 0.0f;
        int ci = (int)f2; ci = ci < 0 ? 0 : (ci > CC - 1 ? CC - 1 : ci);
        g_fs[lane] = (double)f0; g_fe[lane] = (double)f1;
        g_cls[lane] = ci; g_pres[lane] = pres;
    }
    __syncthreads();

    // f64 eval of all K*16 candidates, spread over 64 lanes via LDS
    for (int idx = lane; idx < KK * 16; idx += 64) {
        const int r = idx >> 4, j = idx & 15, sl = j >> 1;
        ulonglong2 pk = cand[((size_t)b * S_SL + sl) * KK + r];
        const unsigned long long key = (j & 1) ? pk.y : pk.x;
        const int col = (int)(unsigned int)(key & 0xffffffffull);
        sd_cost[idx] = eval64(ps, pe, pc, g_fs[r], g_fe[r], g_cls[r], g_pres[r], col);
        sd_col[idx]  = col;
    }
    __syncthreads();

    // lane j<16 owns candidate j of every row, in registers
    double cost_r[KK]; int col_r[KK];
    #pragma unroll
    for (int r = 0; r < KK; r++) {
        if (lane < 16) { cost_r[r] = sd_cost[r * 16 + lane]; col_r[r] = sd_col[r * 16 + lane]; }
        else           { cost_r[r] = DBL_MAX;               col_r[r] = -1; }
    }

    unsigned act = (1u << KK) - 1;

    for (int step = 0; step < KK; step++) {
        // pick: per-row min via 4-level butterfly, then serial over rows (ties -> lower row)
        double bv = DBL_MAX; int br = 0, bc = -1;
        #pragma unroll
        for (int r = 0; r < KK; r++) {
            if (!((act >> r) & 1)) continue;
            double v = cost_r[r]; int c = col_r[r];
            #pragma unroll
            for (int off = 1; off < 16; off <<= 1) {
                double ov = __shfl_xor(v, off, 64);
                int    oc = __shfl_xor(c, off, 64);
                if (ov < v || (ov == v && oc < c)) { v = ov; c = oc; }
            }
            v = __shfl(v, 0, 64); c = __shfl(c, 0, 64);
            if (v < bv) { bv = v; br = r; bc = c; }
        }
        act &= ~(1u << br);
        if (lane == 0) {
            s_prow[step] = br; s_pcol[step] = bc;
            s_pvalid[step] = (bv < VLARGE * 0.5) ? 1 : 0;
            s_cons[step] = bc;
        }
        __syncthreads();

        // kill the consumed column everywhere
        #pragma unroll
        for (int r = 0; r < KK; r++)
            if (col_r[r] == bc) { cost_r[r] = DBL_MAX; col_r[r] = -1; }

        // rescan any (active row, slice) whose BOTH candidates are dead (rare)
        #pragma unroll
        for (int r = 0; r < KK; r++) {
            if (!((act >> r) & 1)) continue;
            unsigned long long dead = __ballot(lane < 16 && cost_r[r] == DBL_MAX);
            unsigned long long both = dead & (dead >> 1) & 0x5555ull;
            while (both) {
                const int e = __ffsll((unsigned long long)both) - 1;
                both &= both - 1;
                const int s = e >> 1;
                const float ffs = (float)g_fs[r], ffe = (float)g_fe[r];
                const int cl = g_cls[r], pres = g_pres[r];
                unsigned long long k1 = KEY_MAX, k2 = KEY_MAX;
                const int basec = s * SLICE;
                for (int t = lane; t < SLICE; t += 64) {
                    const int n = basec + t;
                    bool used = false;
                    for (int u = 0; u <= step; u++) if (s_cons[u] == n) used = true;
                    if (used) continue;
                    float cost;
                    if (!pres) cost = (float)VLARGE;
                    else {
                        const float sg = sigf(ps[n]), eg = sigf(pe[n]);
                        const float q0 = sigf(pc[2 * n]), q1 = sigf(pc[2 * n + 1]);
                        const float d0 = sg - ffs, d1 = eg - ffe;
                        const float sc = (cl == 0) ? q0 : q1;
                        cost = d0 * d0 + d1 * d1 + (q0 * q0 + q1 * q1 - 2.0f * sc + 1.0f);
                    }
                    const unsigned long long kk = packkey(cost, n);
                    if (kk < k2) { if (kk < k1) { k2 = k1; k1 = kk; } else k2 = kk; }
                }
                #pragma unroll
                for (int off = 1; off < 64; off <<= 1) {
                    unsigned long long o1 = __shfl_xor(k1, off, 64);
                    unsigned long long o2 = __shfl_xor(k2, off, 64);
                    merge2(k1, k2, o1, o2);
                }
                k1 = __shfl(k1, 0, 64); k2 = __shfl(k2, 0, 64);
                const int cA = (int)(unsigned int)(k1 & 0xffffffffull);
                const int cB = (int)(unsigned int)(k2 & 0xffffffffull);
                const double costA = (k1 == KEY_MAX) ? DBL_MAX
                    : eval64(ps, pe, pc, g_fs[r], g_fe[r], g_cls[r], g_pres[r], cA);
                const double costB = (k2 == KEY_MAX) ? DBL_MAX
                    : eval64(ps, pe, pc, g_fs[r], g_fe[r], g_cls[r], g_pres[r], cB);
                #pragma unroll
                for (int rr = 0; rr < KK; rr++) {
                    if (rr != r) continue;
                    if (lane == 2 * s)     { cost_r[rr] = costA; col_r[rr] = (k1 == KEY_MAX) ? -1 : cA; }
                    if (lane == 2 * s + 1) { cost_r[rr] = costB; col_r[rr] = (k2 == KEY_MAX) ? -1 : cB; }
                }
            }
        }
    }
    __syncthreads();

    // losses, one pick per lane
    double loss = 0.0, m = 0.0;
    if (lane < KK && s_pvalid[lane]) {
        const int r = s_prow[lane], cidx = s_pcol[lane];
        const double ss = dsig(ps[cidx]);
        const double se = dsig(pe[cidx]);
        const double gs = g_fs[r], ge = g_fe[r];
        const double d0 = ss - gs, d1 = se - ge;
        double acc = d0 * d0 + d1 * d1;

        const double l0 = (double)pc[2 * cidx];
        const double l1 = (double)pc[2 * cidx + 1];
        const double y0 = (g_cls[r] == 0) ? 1.0 : 0.0;
        const double y1 = 1.0 - y0;
        acc += y0 * dsoftplus(-l0) + (1.0 - y0) * dsoftplus(l0)
             + y1 * dsoftplus(-l1) + (1.0 - y1) * dsoftplus(l1);

        const double a1 = fmin(ss, se), b1 = fmax(ss, se);
        const double a2 = fmin(gs, ge), b2 = fmax(gs, ge);
        const double inter = fmax(0.0, fmin(b1, b2) - fmax(a1, a2));
        const double uni   = fmax(1e-8, fmax(b1, b2) - fmin(a1, a2));
        const double iou   = inter / uni;
        const double dcf   = dsig(pcf[cidx]) - iou;
        acc += dcf * dcf;
        loss = acc; m = 1.0;
    }
    #pragma unroll
    for (int off = 1; off < 64; off <<= 1) {
        loss += __shfl_xor(loss, off, 64);
        m    += __shfl_xor(m, off, 64);
    }
    if (lane == 0) { partials[b * 2 + 0] = loss; partials[b * 2 + 1] = m; }
}

__global__ void finalize_kernel(const double* __restrict__ partials,
                                float* __restrict__ out, int out_size) {
    const int t = threadIdx.x;  // 64 threads = 1 wave, one per batch
    for (int i = t; i < out_size; i += 64) out[i] = 0.0f;
    double s = partials[t * 2 + 0];
    double m = partials[t * 2 + 1];
    for (int off = 32; off > 0; off >>= 1) {
        s += __shfl_down(s, off, 64);
        m += __shfl_down(m, off, 64);
    }
    if (t == 0) {
        const double total = s / (m + 1e-8);
        out[0] = (float)(m > 0.0 ? total : 0.0);
    }
}

extern "C" void kernel_launch(void* const* d_in, const int* in_sizes, int n_in,
                              void* d_out, int out_size, void* d_ws, size_t ws_size,
                              hipStream_t stream) {
    const float* p_start = (const float*)d_in[0];  // (B, N)
    const float* p_end   = (const float*)d_in[1];  // (B, N)
    const float* p_cls   = (const float*)d_in[2];  // (B, N, C)
    const float* p_conf  = (const float*)d_in[3];  // (B, N)
    const float* gt      = (const float*)d_in[4];  // (B, K, 3)

    ulonglong2* cand     = (ulonglong2*)d_ws;                      // B*S*K*16 B = 80 KiB
    double*     partials = (double*)((char*)d_ws + (size_t)BB * S_SL * KK * sizeof(ulonglong2));

    scan_kernel<<<dim3(S_SL, BB), TPA, 0, stream>>>(p_start, p_end, p_cls, gt, cand);
    match_kernel<<<BB, 64, 0, stream>>>(p_start, p_end, p_cls, p_conf, gt, cand, partials);
    finalize_kernel<<<1, 64, 0, stream>>>(partials, (float*)d_out, out_size);
}

// Round 4
// 173.344 us; speedup vs baseline: 1.4780x; 1.4780x over previous
//
#include <hip/hip_runtime.h>
#include <cfloat>
#include <cmath>

// Problem constants (fixed by the reference setup).
#define BB 64
#define NN 32768
#define CC 2
#define KK 10
#define S_SL 32                // slices of N -> 64 candidates/row, 1 per lane
#define SLICE (NN / S_SL)      // 1024 columns per slice
#define VLARGE 1.0e6
#define KEY_MAX 0xFFFFFFFFFFFFFFFFull
#define BND_MARGIN 1.0e-4      // safety margin on f32->f64 bound consistency

__device__ __forceinline__ float fsig(float x) {
    // fast sigmoid: nomination-only (all greedy decisions re-evaluated in f64)
    return __fdividef(1.0f, 1.0f + __expf(-x));
}
__device__ __forceinline__ double dsig(float x) { return 1.0 / (1.0 + exp(-(double)x)); }
__device__ __forceinline__ double dsoftplus(double x) {
    return fmax(x, 0.0) + log1p(exp(-fabs(x)));
}
// cost >= 0 (sum of squares form), so f32 bits are monotone as u32.
__device__ __forceinline__ unsigned long long packkey(float v, int c) {
    return ((unsigned long long)__float_as_uint(v) << 32) | (unsigned int)c;
}
__device__ __forceinline__ void merge2(unsigned long long& a1, unsigned long long& a2,
                                       unsigned long long b1, unsigned long long b2) {
    unsigned long long lo = a1 < b1 ? a1 : b1;
    unsigned long long hi = a1 < b1 ? b1 : a1;
    unsigned long long mb = a2 < b2 ? a2 : b2;
    a2 = hi < mb ? hi : mb;
    a1 = lo;
}
// f32 nomination cost — IDENTICAL expression in scan and rescan paths.
__device__ __forceinline__ float costf(float xs, float xe, float xc0, float xc1,
                                       float ffs, float ffe, int cls, int pres) {
    if (!pres) return (float)VLARGE;
    const float s = fsig(xs), e = fsig(xe), q0 = fsig(xc0), q1 = fsig(xc1);
    const float t0 = q0 - 1.0f, t1 = q1 - 1.0f;
    const float cp = (cls == 0) ? fmaf(t0, t0, q1 * q1) : fmaf(t1, t1, q0 * q0);
    const float d0 = s - ffs, d1 = e - ffe;
    return fmaf(d0, d0, fmaf(d1, d1, cp));
}
// f64 exact cost — association matches numpy reference bit-for-bit (verified r1/r3: absmax 0).
__device__ __forceinline__ double eval64(const float* ps, const float* pe, const float* pc,
                                         double fs, double fe, int cls, int pres, int col) {
    if (!pres) return VLARGE;
    const double s  = dsig(ps[col]);
    const double e  = dsig(pe[col]);
    const double q0 = dsig(pc[2 * col]);
    const double q1 = dsig(pc[2 * col + 1]);
    const double d0 = s - fs, d1 = e - fe;
    const double sc = (cls == 0) ? q0 : q1;
    return d0 * d0 + d1 * d1 + (q0 * q0 + q1 * q1 - 2.0 * sc + 1.0);
}

// ---------------- Kernel A: one wave per (slice, batch); per-row top-2 per slice ----------------
__global__ __launch_bounds__(64)
void scan_kernel(const float* __restrict__ p_start, const float* __restrict__ p_end,
                 const float* __restrict__ p_cls, const float* __restrict__ gt,
                 ulonglong2* __restrict__ cand) {
    const int sl = blockIdx.x, b = blockIdx.y, j = threadIdx.x;
    const float2* ps2 = (const float2*)(p_start + (size_t)b * NN);
    const float2* pe2 = (const float2*)(p_end   + (size_t)b * NN);
    const float4* pc4 = (const float4*)(p_cls   + (size_t)b * NN * CC);

    float rfs[KK], rfe[KK]; int rcl[KK], rpres[KK];
    #pragma unroll
    for (int k = 0; k < KK; k++) {
        float f0 = gt[((size_t)b * KK + k) * 3 + 0];
        float f1 = gt[((size_t)b * KK + k) * 3 + 1];
        float f2 = gt[((size_t)b * KK + k) * 3 + 2];
        int pres = !(isnan(f0) || isnan(f1) || isnan(f2));
        if (isnan(f0)) f0 = 0.0f;
        if (isnan(f1)) f1 = 0.0f;
        if (isnan(f2)) f2 = 0.0f;
        int ci = (int)f2; ci = ci < 0 ? 0 : (ci > CC - 1 ? CC - 1 : ci);
        rfs[k] = f0; rfe[k] = f1; rcl[k] = ci; rpres[k] = pres;
    }

    float v1[KK], v2[KK]; int c1[KK], c2[KK];
    #pragma unroll
    for (int k = 0; k < KK; k++) { v1[k] = FLT_MAX; v2[k] = FLT_MAX; c1[k] = 0x7fffffff; c2[k] = 0x7fffffff; }

    const int base = sl * SLICE;
    #pragma unroll
    for (int it = 0; it < SLICE / 128; it++) {          // 8 iters, 2 cols each
        const int pidx = (base >> 1) + it * 64 + j;
        const float2 sv = ps2[pidx];
        const float2 ev = pe2[pidx];
        const float4 cv = pc4[pidx];
        #pragma unroll
        for (int h = 0; h < 2; h++) {
            const int n = 2 * pidx + h;
            const float s  = fsig(h ? sv.y : sv.x);
            const float e  = fsig(h ? ev.y : ev.x);
            const float q0 = fsig(h ? cv.z : cv.x);
            const float q1 = fsig(h ? cv.w : cv.y);
            const float t0 = q0 - 1.0f, t1 = q1 - 1.0f;
            const float cp0 = fmaf(t0, t0, q1 * q1);
            const float cp1 = fmaf(t1, t1, q0 * q0);
            #pragma unroll
            for (int k = 0; k < KK; k++) {
                const float d0 = s - rfs[k], d1 = e - rfe[k];
                float cost = fmaf(d0, d0, fmaf(d1, d1, (rcl[k] == 0) ? cp0 : cp1));
                if (!rpres[k]) cost = (float)VLARGE;
                // n ascends per thread -> strict < keeps lowest col on ties
                const bool lt1 = cost < v1[k], lt2 = cost < v2[k];
                v2[k] = lt2 ? (lt1 ? v1[k] : cost) : v2[k];
                c2[k] = lt2 ? (lt1 ? c1[k] : n)    : c2[k];
                v1[k] = lt1 ? cost : v1[k];
                c1[k] = lt1 ? n    : c1[k];
            }
        }
    }

    unsigned long long k1[KK], k2[KK];
    #pragma unroll
    for (int k = 0; k < KK; k++) { k1[k] = packkey(v1[k], c1[k]); k2[k] = packkey(v2[k], c2[k]); }
    #pragma unroll
    for (int off = 1; off < 64; off <<= 1) {
        #pragma unroll
        for (int k = 0; k < KK; k++) {
            unsigned long long o1 = __shfl_xor(k1[k], off, 64);
            unsigned long long o2 = __shfl_xor(k2[k], off, 64);
            merge2(k1[k], k2[k], o1, o2);
        }
    }
    if (j == 0) {
        #pragma unroll
        for (int k = 0; k < KK; k++) {
            ulonglong2 pk; pk.x = k1[k]; pk.y = k2[k];
            cand[((size_t)b * S_SL + sl) * KK + k] = pk;
        }
    }
}

// ---------------- Kernel B: single wave per batch; lazy-bound greedy + losses ----------------
__global__ __launch_bounds__(64)
void match_kernel(const float* __restrict__ p_start, const float* __restrict__ p_end,
                  const float* __restrict__ p_cls, const float* __restrict__ p_conf,
                  const float* __restrict__ gt, const ulonglong2* __restrict__ cand,
                  double* __restrict__ partials) {
    const int b = blockIdx.x, j = threadIdx.x;
    const int s_my = j >> 1;
    const float* ps  = p_start + (size_t)b * NN;
    const float* pe  = p_end   + (size_t)b * NN;
    const float* pc  = p_cls   + (size_t)b * NN * CC;
    const float* pcf = p_conf  + (size_t)b * NN;

    __shared__ double gfs[KK], gfe[KK];
    __shared__ int    gcls[KK], gpres[KK];
    __shared__ int    s_prow[KK], s_pcol[KK], s_pvalid[KK], s_cons[KK];

    // load + clean gt row j (lanes 0..9), broadcast via shfl
    float myf0 = 0.0f, myf1 = 0.0f; int myci = 0, mypres = 1;
    if (j < KK) {
        float f0 = gt[((size_t)b * KK + j) * 3 + 0];
        float f1 = gt[((size_t)b * KK + j) * 3 + 1];
        float f2 = gt[((size_t)b * KK + j) * 3 + 2];
        mypres = !(isnan(f0) || isnan(f1) || isnan(f2));
        if (isnan(f0)) f0 = 0.0f;
        if (isnan(f1)) f1 = 0.0f;
        if (isnan(f2)) f2 = 0.0f;
        int ci = (int)f2; ci = ci < 0 ? 0 : (ci > CC - 1 ? CC - 1 : ci);
        myf0 = f0; myf1 = f1; myci = ci;
        gfs[j] = (double)f0; gfe[j] = (double)f1; gcls[j] = ci; gpres[j] = mypres;
    }
    __syncthreads();

    double fsr[KK], fer[KK]; int clsr[KK], presr[KK];
    #pragma unroll
    for (int r = 0; r < KK; r++) {
        fsr[r]  = (double)__shfl(myf0, r, 64);
        fer[r]  = (double)__shfl(myf1, r, 64);
        clsr[r] = __shfl(myci, r, 64);
        presr[r] = __shfl(mypres, r, 64);
    }

    // lane j holds candidate slot j (slice j>>1, rank j&1) for every row
    double val[KK]; int col[KK]; double bnd[KK]; int blive[KK];
    #pragma unroll
    for (int r = 0; r < KK; r++) {
        ulonglong2 pk = cand[((size_t)b * S_SL + s_my) * KK + r];
        unsigned long long key = (j & 1) ? pk.y : pk.x;
        const int c = (int)(unsigned int)(key & 0xffffffffull);
        col[r] = c;
        val[r] = eval64(ps, pe, pc, fsr[r], fer[r], clsr[r], presr[r], c);
    }
    #pragma unroll
    for (int r = 0; r < KK; r++) {
        bnd[r] = __shfl(val[r], j | 1, 64) - BND_MARGIN;  // hidden cols in my slice >= slice 2nd
        blive[r] = 1;
    }

    unsigned act = (1u << KK) - 1;

    for (int step = 0; step < KK; step++) {
        double bv; int br, bc;
        while (true) {
            bv = DBL_MAX; br = 0; bc = -1;
            #pragma unroll
            for (int r = 0; r < KK; r++) {
                if (!((act >> r) & 1)) continue;
                const int pcold = __shfl(col[r], j ^ 1, 64);
                double ev = val[r]; int ec = col[r];
                const bool bothdead = (col[r] < 0) && (pcold < 0);
                if (((j & 1) == 0) && bothdead && blive[r]) { ev = bnd[r]; ec = -2 - s_my; }
                #pragma unroll
                for (int off = 1; off < 64; off <<= 1) {
                    double ov = __shfl_xor(ev, off, 64);
                    int    oc = __shfl_xor(ec, off, 64);
                    if (ov < ev || (ov == ev && oc < ec)) { ev = ov; ec = oc; }
                }
                if (ev < bv) { bv = ev; br = r; bc = ec; }   // uniform; ties -> lower row
            }
            if (bc >= -1) break;        // real column (or fully-exhausted row): done

            // a BOUND won -> resolve: exact rescan of (row br, slice ss). Rare.
            const int ss  = -2 - bc;
            const float ffs = __shfl(myf0, br, 64), ffe = __shfl(myf1, br, 64);
            const int   cb  = __shfl(myci, br, 64);
            const int   pb  = __shfl(mypres, br, 64);
            unsigned long long r1 = KEY_MAX, r2 = KEY_MAX;
            const int cbase = ss * SLICE;
            #pragma unroll 4
            for (int t = j; t < SLICE; t += 64) {
                const int n = cbase + t;
                bool used = false;
                for (int u = 0; u < step; u++) if (s_cons[u] == n) used = true;
                const float cst = costf(ps[n], pe[n], pc[2 * n], pc[2 * n + 1], ffs, ffe, cb, pb);
                const unsigned long long kk = used ? KEY_MAX : packkey(cst, n);
                if (kk < r2) { if (kk < r1) { r2 = r1; r1 = kk; } else r2 = kk; }
            }
            #pragma unroll
            for (int off = 1; off < 64; off <<= 1) {
                unsigned long long o1 = __shfl_xor(r1, off, 64);
                unsigned long long o2 = __shfl_xor(r2, off, 64);
                merge2(r1, r2, o1, o2);
            }
            const int cA = (int)(unsigned int)(r1 & 0xffffffffull);
            const int cB = (int)(unsigned int)(r2 & 0xffffffffull);
            const double dfs = (double)ffs, dfe = (double)ffe;
            const double vA = (r1 == KEY_MAX) ? DBL_MAX : eval64(ps, pe, pc, dfs, dfe, cb, pb, cA);
            const double vB = (r2 == KEY_MAX) ? DBL_MAX : eval64(ps, pe, pc, dfs, dfe, cb, pb, cB);
            #pragma unroll
            for (int rr = 0; rr < KK; rr++) {
                if (rr != br) continue;
                if (s_my == ss) {
                    if ((j & 1) == 0) { val[rr] = vA; col[rr] = (r1 == KEY_MAX) ? -1 : cA; }
                    else              { val[rr] = vB; col[rr] = (r2 == KEY_MAX) ? -1 : cB; }
                    blive[rr] = (r2 != KEY_MAX) ? 1 : 0;
                    bnd[rr]   = (r2 != KEY_MAX) ? (vB - BND_MARGIN) : DBL_MAX;
                }
            }
        }

        act &= ~(1u << br);
        if (j == 0) {
            s_prow[step] = br; s_pcol[step] = bc;
            s_pvalid[step] = (bv < VLARGE * 0.5) && (bc >= 0);
            s_cons[step] = bc;
        }
        __syncthreads();
        if (bc >= 0) {
            #pragma unroll
            for (int r = 0; r < KK; r++)
                if (col[r] == bc) { val[r] = DBL_MAX; col[r] = -1; }
        }
    }

    // losses: one pick per lane
    double loss = 0.0, m = 0.0;
    if (j < KK && s_pvalid[j]) {
        const int r = s_prow[j], cidx = s_pcol[j];
        const double ss = dsig(ps[cidx]);
        const double se = dsig(pe[cidx]);
        const double gs = gfs[r], ge = gfe[r];
        const double d0 = ss - gs, d1 = se - ge;
        double acc = d0 * d0 + d1 * d1;

        const double l0 = (double)pc[2 * cidx];
        const double l1 = (double)pc[2 * cidx + 1];
        const double y0 = (gcls[r] == 0) ? 1.0 : 0.0;
        const double y1 = 1.0 - y0;
        acc += y0 * dsoftplus(-l0) + (1.0 - y0) * dsoftplus(l0)
             + y1 * dsoftplus(-l1) + (1.0 - y1) * dsoftplus(l1);

        const double a1 = fmin(ss, se), b1 = fmax(ss, se);
        const double a2 = fmin(gs, ge), b2 = fmax(gs, ge);
        const double inter = fmax(0.0, fmin(b1, b2) - fmax(a1, a2));
        const double uni   = fmax(1e-8, fmax(b1, b2) - fmin(a1, a2));
        const double iou   = inter / uni;
        const double dcf   = dsig(pcf[cidx]) - iou;
        acc += dcf * dcf;
        loss = acc; m = 1.0;
    }
    #pragma unroll
    for (int off = 1; off < 64; off <<= 1) {
        loss += __shfl_xor(loss, off, 64);
        m    += __shfl_xor(m, off, 64);
    }
    if (j == 0) { partials[b * 2 + 0] = loss; partials[b * 2 + 1] = m; }
}

__global__ void finalize_kernel(const double* __restrict__ partials,
                                float* __restrict__ out, int out_size) {
    const int t = threadIdx.x;
    for (int i = t; i < out_size; i += 64) out[i] = 0.0f;
    double s = partials[t * 2 + 0];
    double m = partials[t * 2 + 1];
    for (int off = 32; off > 0; off >>= 1) {
        s += __shfl_down(s, off, 64);
        m += __shfl_down(m, off, 64);
    }
    if (t == 0) {
        const double total = s / (m + 1e-8);
        out[0] = (float)(m > 0.0 ? total : 0.0);
    }
}

extern "C" void kernel_launch(void* const* d_in, const int* in_sizes, int n_in,
                              void* d_out, int out_size, void* d_ws, size_t ws_size,
                              hipStream_t stream) {
    const float* p_start = (const float*)d_in[0];  // (B, N)
    const float* p_end   = (const float*)d_in[1];  // (B, N)
    const float* p_cls   = (const float*)d_in[2];  // (B, N, C)
    const float* p_conf  = (const float*)d_in[3];  // (B, N)
    const float* gt      = (const float*)d_in[4];  // (B, K, 3)

    ulonglong2* cand     = (ulonglong2*)d_ws;      // B*S*K*16 B = 320 KiB
    double*     partials = (double*)((char*)d_ws + (size_t)BB * S_SL * KK * sizeof(ulonglong2));

    scan_kernel<<<dim3(S_SL, BB), 64, 0, stream>>>(p_start, p_end, p_cls, gt, cand);
    match_kernel<<<BB, 64, 0, stream>>>(p_start, p_end, p_cls, p_conf, gt, cand, partials);
    finalize_kernel<<<1, 64, 0, stream>>>(partials, (float*)d_out, out_size);
}